// Round 19
// baseline (519.213 us; speedup 1.0000x reference)
//
#include <hip/hip_runtime.h>
#include <hip/hip_bf16.h>

#define SEQ 2048
#define HID 4096
#define NHEADS 32
#define HDIM 128
#define LR 8

typedef __attribute__((ext_vector_type(8))) short bf16x8;
typedef __attribute__((ext_vector_type(4))) float f32x4;
typedef __attribute__((ext_vector_type(16))) float f32x16;

typedef __attribute__((address_space(3))) void lds_void;
typedef const __attribute__((address_space(1))) void glb_void;

static __device__ __forceinline__ float bf2f(__hip_bfloat16 v) { return __bfloat162float(v); }
static __device__ __forceinline__ __hip_bfloat16 f2bf(float v) { return __float2bfloat16(v); }

static __device__ __forceinline__ unsigned pkbf(float lo, float hi2) {
  __hip_bfloat16 l = __float2bfloat16(lo), h2 = __float2bfloat16(hi2);
  unsigned short ul = *reinterpret_cast<unsigned short*>(&l);
  unsigned short uh = *reinterpret_cast<unsigned short*>(&h2);
  return ((unsigned)uh << 16) | ul;
}

static __device__ __forceinline__ float bfbits2f(short s) {
  union { unsigned u; float f; } c;
  c.u = ((unsigned)(unsigned short)s) << 16;
  return c.f;
}

// ---------------------------------------------------------------- fp32 -> bf16 (Wo)
__global__ __launch_bounds__(256) void conv_f32_bf16(const float* __restrict__ src,
                                                     __hip_bfloat16* __restrict__ dst,
                                                     int n4) {
  const int i = blockIdx.x * 256 + threadIdx.x;
  if (i >= n4) return;
  const float4 v = reinterpret_cast<const float4*>(src)[i];
  union { __hip_bfloat16 h[4]; ushort4 u; } pk;
  pk.h[0] = f2bf(v.x); pk.h[1] = f2bf(v.y); pk.h[2] = f2bf(v.z); pk.h[3] = f2bf(v.w);
  reinterpret_cast<ushort4*>(dst)[i] = pk.u;
}

// ---------------------------------------------------------------- fp32 -> bf16, 3 weights, one dispatch
__global__ __launch_bounds__(256) void conv_w3(const float* __restrict__ w0,
                                               const float* __restrict__ w1,
                                               const float* __restrict__ w2,
                                               __hip_bfloat16* __restrict__ dst) {
  const int z = blockIdx.z;
  const float* src = (z == 0) ? w0 : (z == 1) ? w1 : w2;
  __hip_bfloat16* d = dst + (size_t)z * HID * HID;
  const int i = blockIdx.x * 256 + threadIdx.x;  // over HID*HID/4
  const float4 v = reinterpret_cast<const float4*>(src)[i];
  union { __hip_bfloat16 h[4]; ushort4 u; } pk;
  pk.h[0] = f2bf(v.x); pk.h[1] = f2bf(v.y); pk.h[2] = f2bf(v.z); pk.h[3] = f2bf(v.w);
  reinterpret_cast<ushort4*>(d)[i] = pk.u;
}

// ---------------------------------------------------------------- t = x @ {Aq,Ak,Av}^T + x->bf16
// R19: ONE pass over x per row (was 3): wave computes all 24 rank-8 dots.
// A matrices = 384 KB total -> L2-resident across rows.
__global__ __launch_bounds__(256) void lora_t(const float* __restrict__ x,
                                              const float* __restrict__ Aq,
                                              const float* __restrict__ Ak,
                                              const float* __restrict__ Av,
                                              float* __restrict__ tq,
                                              float* __restrict__ tk,
                                              float* __restrict__ tv,
                                              __hip_bfloat16* __restrict__ xb) {
  const int s = blockIdx.x * 4 + (threadIdx.x >> 6);  // one wave per row
  const int lane = threadIdx.x & 63;
  float acc[3][LR];
#pragma unroll
  for (int q = 0; q < 3; ++q)
#pragma unroll
    for (int r = 0; r < LR; ++r) acc[q][r] = 0.0f;
  const float4* xr = reinterpret_cast<const float4*>(x + (size_t)s * HID);
  const float* Aall[3] = {Aq, Ak, Av};
  for (int c = lane; c < HID / 4; c += 64) {
    const float4 xv = xr[c];
    union { __hip_bfloat16 h[4]; ushort4 u; } pk;
    pk.h[0] = f2bf(xv.x); pk.h[1] = f2bf(xv.y); pk.h[2] = f2bf(xv.z); pk.h[3] = f2bf(xv.w);
    reinterpret_cast<ushort4*>(xb + (size_t)s * HID)[c] = pk.u;
#pragma unroll
    for (int q = 0; q < 3; ++q)
#pragma unroll
      for (int r = 0; r < LR; ++r) {
        const float4 av = reinterpret_cast<const float4*>(Aall[q] + r * HID)[c];
        acc[q][r] += xv.x * av.x + xv.y * av.y + xv.z * av.z + xv.w * av.w;
      }
  }
#pragma unroll
  for (int q = 0; q < 3; ++q) {
    float* t = (q == 0) ? tq : (q == 1) ? tk : tv;
#pragma unroll
    for (int r = 0; r < LR; ++r) {
      float vv = acc[q][r];
#pragma unroll
      for (int off = 32; off > 0; off >>= 1) vv += __shfl_down(vv, off);
      if (lane == 0) t[s * LR + r] = vv;
    }
  }
}

// ---------------------------------------------------------------- RoPE cos/sin tables [S][64]
__global__ __launch_bounds__(256) void rope_tables(float* __restrict__ cosb,
                                                   float* __restrict__ sinb) {
  const int i = blockIdx.x * 256 + threadIdx.x;
  const int s = i >> 6, d = i & 63;
  const float invf = powf(10000.0f, -(float)d * (1.0f / 64.0f));
  const float ang = (float)s * invf;
  cosb[i] = cosf(ang);
  sinb[i] = sinf(ang);
}

// ---------------------------------------------------------------- counted-vmcnt GEMM (R7 core)
// z==2 (V): epilogue writes transpose. z==1 (K): epilogue RoPE via LDS exchange.
template <bool LORA>
__global__ __launch_bounds__(512, 2) void gemm2(const __hip_bfloat16* __restrict__ X,
                                                const __hip_bfloat16* __restrict__ wqkv,
                                                const float* __restrict__ tq,
                                                const float* __restrict__ tk,
                                                const float* __restrict__ tv,
                                                const float* __restrict__ Bq,
                                                const float* __restrict__ Bk,
                                                const float* __restrict__ Bv,
                                                const float* __restrict__ cosb,
                                                const float* __restrict__ sinb,
                                                __hip_bfloat16* __restrict__ qb,
                                                __hip_bfloat16* __restrict__ kb,
                                                __hip_bfloat16* __restrict__ vtb,
                                                float* __restrict__ outf) {
  __shared__ __hip_bfloat16 Al[2][2][128][32];
  __shared__ __hip_bfloat16 Bl[2][2][256][32];
  const int z = blockIdx.z;
  const __hip_bfloat16* W = wqkv + (size_t)z * HID * HID;
  const float* T = (z == 0) ? tq : (z == 1) ? tk : tv;
  const float* BL = (z == 0) ? Bq : (z == 1) ? Bk : Bv;

  const int tid = threadIdx.x;
  const int lane = tid & 63;
  const int w = tid >> 6;
  const int wm = w >> 2;
  const int wn = w & 3;
  const int g = lane >> 4, lr = lane & 15;

  const int fid = blockIdx.x + (blockIdx.y << 4);
  const int xcd = fid & 7;
  const int j8 = fid >> 3;
  const int rowBase = (j8 >> 1) * 128;
  const int colBase = (xcd * 2 + (j8 & 1)) * 256;

  const int sA = w * 64 + lane;
  const int rA = sA >> 2, cA = sA & 3;
  const __hip_bfloat16* Ag = X + (size_t)(rowBase + rA) * HID + ((cA ^ ((rA >> 1) & 3)) * 8);
  const int sB0 = (w * 2) * 64 + lane;
  const int sB1 = (w * 2 + 1) * 64 + lane;
  const int rB0 = sB0 >> 2, cB0 = sB0 & 3;
  const int rB1 = sB1 >> 2, cB1 = sB1 & 3;
  const __hip_bfloat16* Bg0 = W + (size_t)(colBase + rB0) * HID + ((cB0 ^ ((rB0 >> 1) & 3)) * 8);
  const __hip_bfloat16* Bg1 = W + (size_t)(colBase + rB1) * HID + ((cB1 ^ ((rB1 >> 1) & 3)) * 8);

#define STG2(buf_, kh_, kk_)                                                        \
  do {                                                                              \
    __builtin_amdgcn_global_load_lds((glb_void*)(Ag + (kk_) + (kh_) * 32),          \
        (lds_void*)(&Al[buf_][kh_][0][0] + w * 512), 16, 0, 0);                     \
    __builtin_amdgcn_global_load_lds((glb_void*)(Bg0 + (kk_) + (kh_) * 32),         \
        (lds_void*)(&Bl[buf_][kh_][0][0] + (w * 2) * 512), 16, 0, 0);               \
    __builtin_amdgcn_global_load_lds((glb_void*)(Bg1 + (kk_) + (kh_) * 32),         \
        (lds_void*)(&Bl[buf_][kh_][0][0] + (w * 2 + 1) * 512), 16, 0, 0);           \
  } while (0)

  f32x4 acc[4][4];
#pragma unroll
  for (int m = 0; m < 4; ++m)
#pragma unroll
    for (int n = 0; n < 4; ++n)
#pragma unroll
      for (int e = 0; e < 4; ++e) acc[m][n][e] = 0.0f;

  const int ch = (g ^ ((lr >> 1) & 3)) * 8;

  STG2(0, 0, 0);
  __builtin_amdgcn_sched_barrier(0);
  STG2(0, 1, 0);

  for (int j = 0; j < 64; ++j) {
    const int cur = j & 1, nxt = cur ^ 1;
    const int kn = (j < 63 ? j + 1 : 63) * 64;  // j==63: redundant re-stage keeps FIFO
#pragma unroll
    for (int kh = 0; kh < 2; ++kh) {
      asm volatile("s_waitcnt vmcnt(3) lgkmcnt(0)" ::: "memory");
      __builtin_amdgcn_s_barrier();
      __builtin_amdgcn_sched_barrier(0);
      bf16x8 af[4], bfr[4];
#pragma unroll
      for (int m = 0; m < 4; ++m)
        af[m] = *reinterpret_cast<const bf16x8*>(&Al[cur][kh][wm * 64 + m * 16 + lr][ch]);
#pragma unroll
      for (int n = 0; n < 4; ++n)
        bfr[n] = *reinterpret_cast<const bf16x8*>(&Bl[cur][kh][wn * 64 + n * 16 + lr][ch]);
      if (kh == 0) STG2(nxt, 0, kn); else STG2(nxt, 1, kn);
      __builtin_amdgcn_sched_barrier(0);
      __builtin_amdgcn_s_setprio(1);
#pragma unroll
      for (int m = 0; m < 4; ++m)
#pragma unroll
        for (int n = 0; n < 4; ++n)
          acc[m][n] = __builtin_amdgcn_mfma_f32_16x16x32_bf16(af[m], bfr[n], acc[m][n], 0, 0, 0);
      __builtin_amdgcn_s_setprio(0);
    }
  }
#undef STG2

  const int orow0 = rowBase + wm * 64 + g * 4;
  const int ocol0 = colBase + wn * 64 + lr;
  if constexpr (LORA) {
    float bl[4][8];
#pragma unroll
    for (int n = 0; n < 4; ++n) {
      const int cc = ocol0 + n * 16;
      const int fc = (cc < HID / 2) ? (2 * cc) : (2 * (cc - HID / 2) + 1);
#pragma unroll
      for (int e = 0; e < 8; ++e) bl[n][e] = BL[fc * LR + e];
    }
    __hip_bfloat16 vv[4][4][4];
#pragma unroll
    for (int m = 0; m < 4; ++m) {
      float tr[4][8];
#pragma unroll
      for (int r2 = 0; r2 < 4; ++r2)
#pragma unroll
        for (int e = 0; e < 8; ++e) tr[r2][e] = T[(size_t)(orow0 + m * 16 + r2) * LR + e];
#pragma unroll
      for (int n = 0; n < 4; ++n)
#pragma unroll
        for (int r2 = 0; r2 < 4; ++r2) {
          float dot = 0.0f;
#pragma unroll
          for (int e = 0; e < 8; ++e) dot += tr[r2][e] * bl[n][e];
          vv[m][n][r2] = f2bf(acc[m][n][r2] + 2.0f * dot);
        }
    }
    if (z == 0) {
#pragma unroll
      for (int m = 0; m < 4; ++m)
#pragma unroll
        for (int n = 0; n < 4; ++n)
#pragma unroll
          for (int r2 = 0; r2 < 4; ++r2)
            qb[(size_t)(orow0 + m * 16 + r2) * HID + ocol0 + n * 16] = vv[m][n][r2];
    } else if (z == 2) {
#pragma unroll
      for (int m = 0; m < 4; ++m)
#pragma unroll
        for (int n = 0; n < 4; ++n) {
          const int cc = ocol0 + n * 16;
          union { __hip_bfloat16 h[4]; ushort4 u; } pk;
#pragma unroll
          for (int r2 = 0; r2 < 4; ++r2) pk.h[r2] = vv[m][n][r2];
          *reinterpret_cast<ushort4*>(vtb + (size_t)cc * SEQ + orow0 + m * 16) = pk.u;
        }
    } else {
      // K: RoPE via LDS pair-exchange; drain pending gload_lds into buffer 0 first
      asm volatile("s_waitcnt vmcnt(0)" ::: "memory");
      __syncthreads();
      __hip_bfloat16* ex = &Bl[0][0][0][0];  // 64 KB = [128][256]
#pragma unroll
      for (int m = 0; m < 4; ++m)
#pragma unroll
        for (int n = 0; n < 4; ++n) {
          const int rl = wm * 64 + m * 16 + g * 4;
          const int ccl = wn * 64 + n * 16 + lr;
#pragma unroll
          for (int r2 = 0; r2 < 4; ++r2) ex[(rl + r2) * 256 + ccl] = vv[m][n][r2];
        }
      __syncthreads();
#pragma unroll
      for (int m = 0; m < 4; ++m)
#pragma unroll
        for (int n = 0; n < 4; ++n) {
          const int rl = wm * 64 + m * 16 + g * 4;
          const int ccl = wn * 64 + n * 16 + lr;
          const int d = ccl & 127;
          const int dd = d & 63;
#pragma unroll
          for (int r2 = 0; r2 < 4; ++r2) {
            const int rowg = rowBase + rl + r2;
            const float c = cosb[(size_t)rowg * 64 + dd];
            const float s = sinb[(size_t)rowg * 64 + dd];
            const float v0 = bf2f(vv[m][n][r2]);
            const float pv = bf2f(ex[(rl + r2) * 256 + (ccl ^ 64)]);
            const float outv = (d < 64) ? (v0 * c - pv * s) : (pv * s + v0 * c);
            kb[(size_t)rowg * HID + colBase + ccl] = f2bf(outv);
          }
        }
    }
  } else {
#pragma unroll
    for (int m = 0; m < 4; ++m)
#pragma unroll
      for (int n = 0; n < 4; ++n)
#pragma unroll
        for (int r2 = 0; r2 < 4; ++r2)
          outf[(size_t)(orow0 + m * 16 + r2) * HID + ocol0 + n * 16] = acc[m][n][r2];
  }
}

// ---------------------------------------------------------------- causal flash attention v4 + q-RoPE + T5
#define STAGE(buf_, kvb_)                                                                   \
  do {                                                                                      \
    _Pragma("unroll") for (int i_ = 0; i_ < 4; ++i_) {                                      \
      const int sb_ = (w * 4 + i_) * 64;                                                    \
      {                                                                                     \
        const int slot_ = sb_ + lane;                                                       \
        const int rr_ = slot_ >> 4, cc_ = slot_ & 15;                                       \
        __builtin_amdgcn_global_load_lds(                                                   \
            (glb_void*)(kg + (size_t)((kvb_) + rr_) * HID + h * HDIM +                      \
                        ((cc_ ^ (rr_ & 15)) << 3)),                                         \
            (lds_void*)(&Ks[buf_][sb_ * 8]), 16, 0, 0);                                     \
      }                                                                                     \
      {                                                                                     \
        const int slot_ = sb_ + lane;                                                       \
        const int rr_ = slot_ >> 3, cc_ = slot_ & 7;                                        \
        __builtin_amdgcn_global_load_lds(                                                   \
            (glb_void*)(vt + ((size_t)h * HDIM + rr_) * SEQ + (kvb_) +                      \
                        ((cc_ ^ (rr_ & 7)) << 3)),                                          \
            (lds_void*)(&Vs[buf_][sb_ * 8]), 16, 0, 0);                                     \
      }                                                                                     \
    }                                                                                       \
  } while (0)

__global__ __launch_bounds__(256, 2) void flash_attn4(const __hip_bfloat16* __restrict__ qg,
                                                      const __hip_bfloat16* __restrict__ kg,
                                                      const __hip_bfloat16* __restrict__ vt,
                                                      const float* __restrict__ cosb,
                                                      const float* __restrict__ sinb,
                                                      __hip_bfloat16* __restrict__ o) {
  __shared__ __hip_bfloat16 Ks[2][64 * 128];
  __shared__ __hip_bfloat16 Vs[2][128 * 64];
  const int tid = threadIdx.x;
  const int lane = tid & 63;
  const int w = tid >> 6;
  const int ql = lane & 31;
  const int hi = lane >> 5;
  const int bx = blockIdx.x;
  const int h = bx & 31;
  const int strip = (bx < 256) ? (bx >> 5) : (15 - ((bx - 256) >> 5));
  const float scale = 0.088388347648318447f;

  const int q0 = strip * 128 + w * 32;
  const int nt = 2 * strip + 2;
  const int qgl = q0 + ql;

  bf16x8 bq[8];
#pragma unroll
  for (int sl = 0; sl < 8; ++sl)
    bq[sl] = *reinterpret_cast<const bf16x8*>(qg + (size_t)qgl * HID + h * HDIM + sl * 16 + hi * 8);

  // ---- q-RoPE in registers
  {
    const float* cb = cosb + (size_t)qgl * 64;
    const float* sbl = sinb + (size_t)qgl * 64;
#pragma unroll
    for (int sl = 0; sl < 4; ++sl) {
      const int d0 = sl * 16 + hi * 8;
      const float4 c0 = *reinterpret_cast<const float4*>(cb + d0);
      const float4 c1 = *reinterpret_cast<const float4*>(cb + d0 + 4);
      const float4 s0 = *reinterpret_cast<const float4*>(sbl + d0);
      const float4 s1 = *reinterpret_cast<const float4*>(sbl + d0 + 4);
      const float cc[8] = {c0.x, c0.y, c0.z, c0.w, c1.x, c1.y, c1.z, c1.w};
      const float ss[8] = {s0.x, s0.y, s0.z, s0.w, s1.x, s1.y, s1.z, s1.w};
      float y1[8], y2[8];
#pragma unroll
      for (int e = 0; e < 8; ++e) {
        const float x1 = bfbits2f(bq[sl][e]);
        const float x2 = bfbits2f(bq[sl + 4][e]);
        y1[e] = x1 * cc[e] - x2 * ss[e];
        y2[e] = x1 * ss[e] + x2 * cc[e];
      }
      union { unsigned u[4]; bf16x8 v; } p1, p2;
#pragma unroll
      for (int e2 = 0; e2 < 4; ++e2) {
        p1.u[e2] = pkbf(y1[2 * e2], y1[2 * e2 + 1]);
        p2.u[e2] = pkbf(y2[2 * e2], y2[2 * e2 + 1]);
      }
      bq[sl] = p1.v;
      bq[sl + 4] = p2.v;
    }
  }

  f32x16 accO[4];
#pragma unroll
  for (int db = 0; db < 4; ++db)
#pragma unroll
    for (int e = 0; e < 16; ++e) accO[db][e] = 0.0f;
  float m_run = -1e30f, lsum = 0.0f;

  int cur = 0;
  STAGE(0, 0);
  asm volatile("s_waitcnt vmcnt(0)");
  __syncthreads();

  for (int t = 0; t < nt; ++t) {
    const int kvb = t * 64;
    if (t + 1 < nt) STAGE(cur ^ 1, (t + 1) * 64);
    if (kvb <= q0 + 31) {
      f32x16 sc[2];
#pragma unroll
      for (int sub = 0; sub < 2; ++sub) {
#pragma unroll
        for (int e = 0; e < 16; ++e) sc[sub][e] = 0.0f;
        const int krow = sub * 32 + ql;
        __builtin_amdgcn_s_setprio(1);
#pragma unroll
        for (int sl = 0; sl < 8; ++sl) {
          const int chh = (sl * 2 + hi) ^ (ql & 15);
          bf16x8 ak = *reinterpret_cast<const bf16x8*>(&Ks[cur][krow * 128 + chh * 8]);
          sc[sub] = __builtin_amdgcn_mfma_f32_32x32x16_bf16(ak, bq[sl], sc[sub], 0, 0, 0);
        }
        __builtin_amdgcn_s_setprio(0);
      }
      float smax = -3.0e38f;
      if (kvb + 63 > q0) {
#pragma unroll
        for (int sub = 0; sub < 2; ++sub)
#pragma unroll
          for (int r = 0; r < 16; ++r) {
            const int kvg = kvb + sub * 32 + (r & 3) + 8 * (r >> 2) + 4 * hi;
            float v2 = sc[sub][r] * scale;
            v2 = (kvg > qgl) ? -3.0e38f : v2;
            sc[sub][r] = v2;
            smax = fmaxf(smax, v2);
          }
      } else {
#pragma unroll
        for (int sub = 0; sub < 2; ++sub)
#pragma unroll
          for (int r = 0; r < 16; ++r) {
            const float v2 = sc[sub][r] * scale;
            sc[sub][r] = v2;
            smax = fmaxf(smax, v2);
          }
      }
      smax = fmaxf(smax, __shfl_xor(smax, 32));
      if (__any(smax > m_run + 8.0f)) {
        const float mnew = fmaxf(m_run, smax);
        const float sca = __expf(m_run - mnew);
        m_run = mnew;
        lsum *= sca;
#pragma unroll
        for (int r = 0; r < 16; ++r) {
          const float sr = __shfl(sca, (r & 3) + 8 * (r >> 2) + 4 * hi);
#pragma unroll
          for (int db = 0; db < 4; ++db) accO[db][r] *= sr;
        }
      }
      float psum = 0.0f;
#pragma unroll
      for (int sub = 0; sub < 2; ++sub)
#pragma unroll
        for (int r = 0; r < 16; ++r) {
          const float p = __expf(sc[sub][r] - m_run);
          sc[sub][r] = p;
          psum += p;
        }
      psum += __shfl_xor(psum, 32);
      lsum += psum;
      bf16x8 pa[4];
#pragma unroll
      for (int sub = 0; sub < 2; ++sub) {
        const unsigned A0 = pkbf(sc[sub][0], sc[sub][1]);
        const unsigned C0 = pkbf(sc[sub][2], sc[sub][3]);
        const unsigned B0 = pkbf(sc[sub][4], sc[sub][5]);
        const unsigned D0 = pkbf(sc[sub][6], sc[sub][7]);
        const unsigned A1 = pkbf(sc[sub][8], sc[sub][9]);
        const unsigned C1 = pkbf(sc[sub][10], sc[sub][11]);
        const unsigned B1 = pkbf(sc[sub][12], sc[sub][13]);
        const unsigned D1 = pkbf(sc[sub][14], sc[sub][15]);
        const unsigned sA0 = (unsigned)__shfl_xor((int)A0, 32);
        const unsigned sB0 = (unsigned)__shfl_xor((int)B0, 32);
        const unsigned sC0 = (unsigned)__shfl_xor((int)C0, 32);
        const unsigned sD0 = (unsigned)__shfl_xor((int)D0, 32);
        const unsigned sA1 = (unsigned)__shfl_xor((int)A1, 32);
        const unsigned sB1 = (unsigned)__shfl_xor((int)B1, 32);
        const unsigned sC1 = (unsigned)__shfl_xor((int)C1, 32);
        const unsigned sD1 = (unsigned)__shfl_xor((int)D1, 32);
        union { unsigned u[4]; bf16x8 v; } f0, f1;
        f0.u[0] = hi ? sB0 : A0;
        f0.u[1] = hi ? sD0 : C0;
        f0.u[2] = hi ? B0 : sA0;
        f0.u[3] = hi ? D0 : sC0;
        f1.u[0] = hi ? sB1 : A1;
        f1.u[1] = hi ? sD1 : C1;
        f1.u[2] = hi ? B1 : sA1;
        f1.u[3] = hi ? D1 : sC1;
        pa[sub * 2 + 0] = f0.v;
        pa[sub * 2 + 1] = f1.v;
      }
      __builtin_amdgcn_s_setprio(1);
#pragma unroll
      for (int db = 0; db < 4; ++db) {
        const int vrow = db * 32 + ql;
#pragma unroll
        for (int ks = 0; ks < 4; ++ks) {
          const int chh = (ks * 2 + hi) ^ (ql & 7);
          bf16x8 bv = *reinterpret_cast<const bf16x8*>(&Vs[cur][vrow * 64 + chh * 8]);
          accO[db] = __builtin_amdgcn_mfma_f32_32x32x16_bf16(pa[ks], bv, accO[db], 0, 0, 0);
        }
      }
      __builtin_amdgcn_s_setprio(0);
    }
    asm volatile("s_waitcnt vmcnt(0)");
    __syncthreads();
    cur ^= 1;
  }
  const float il = 1.0f / lsum;
#pragma unroll
  for (int r = 0; r < 16; ++r) {
    const int rb = (r & 3) + 8 * (r >> 2);
    const float ir = __shfl(il, rb + 4 * hi);
    const int qrow = q0 + rb + 4 * hi;
#pragma unroll
    for (int db = 0; db < 4; ++db)
      o[(size_t)qrow * HID + h * HDIM + db * 32 + ql] = f2bf(accO[db][r] * ir);
  }
}

// ----------------------------------------------------------------
extern "C" void kernel_launch(void* const* d_in, const int* in_sizes, int n_in,
                              void* d_out, int out_size, void* d_ws, size_t ws_size,
                              hipStream_t stream) {
  (void)in_sizes; (void)n_in; (void)out_size; (void)ws_size;
  const float* x  = (const float*)d_in[0];
  const float* Wq = (const float*)d_in[1];
  const float* Wk = (const float*)d_in[2];
  const float* Wv = (const float*)d_in[3];
  const float* Wo = (const float*)d_in[4];
  const float* Aq = (const float*)d_in[5];
  const float* Bq = (const float*)d_in[6];
  const float* Ak = (const float*)d_in[7];
  const float* Bk = (const float*)d_in[8];
  const float* Av = (const float*)d_in[9];
  const float* Bv = (const float*)d_in[10];
  float* out = (float*)d_out;

  char* p = (char*)d_ws;
  __hip_bfloat16* xb   = (__hip_bfloat16*)p; p += (size_t)SEQ * HID * 2;       // reused as ab
  __hip_bfloat16* wqkv = (__hip_bfloat16*)p; p += (size_t)3 * HID * HID * 2;   // [0:32M] reused for Wo
  __hip_bfloat16* qb   = (__hip_bfloat16*)p; p += (size_t)SEQ * HID * 2;
  __hip_bfloat16* kb   = (__hip_bfloat16*)p; p += (size_t)SEQ * HID * 2;
  __hip_bfloat16* vtb  = (__hip_bfloat16*)p; p += (size_t)SEQ * HID * 2;       // V^T, written by gemm z==2
  float* tq   = (float*)p; p += SEQ * LR * 4;
  float* tk   = (float*)p; p += SEQ * LR * 4;
  float* tv   = (float*)p; p += SEQ * LR * 4;
  float* cosb = (float*)p; p += SEQ * 64 * 4;
  float* sinb = (float*)p; p += SEQ * 64 * 4;
  __hip_bfloat16* ab = xb;  // x no longer needed after QKV GEMMs

  lora_t<<<SEQ / 4, 256, 0, stream>>>(x, Aq, Ak, Av, tq, tk, tv, xb);
  rope_tables<<<SEQ * 64 / 256, 256, 0, stream>>>(cosb, sinb);
  conv_w3<<<dim3(HID * HID / 1024, 1, 3), 256, 0, stream>>>(Wq, Wk, Wv, wqkv);

  gemm2<true><<<dim3(16, 16, 3), 512, 0, stream>>>(xb, wqkv, tq, tk, tv, Bq, Bk, Bv,
                                                   cosb, sinb, qb, kb, vtb, nullptr);

  flash_attn4<<<512, 256, 0, stream>>>(qb, kb, vtb, cosb, sinb, ab);

  conv_f32_bf16<<<HID * HID / 1024, 256, 0, stream>>>(Wo, wqkv, HID * HID / 4);
  gemm2<false><<<dim3(16, 16, 1), 512, 0, stream>>>(ab, wqkv, nullptr, nullptr, nullptr,
                                                    nullptr, nullptr, nullptr,
                                                    cosb, sinb, nullptr, nullptr, nullptr, out);
}

// Round 20
// 473.840 us; speedup vs baseline: 1.0958x; 1.0958x over previous
//
#include <hip/hip_runtime.h>
#include <hip/hip_bf16.h>

#define SEQ 2048
#define HID 4096
#define NHEADS 32
#define HDIM 128
#define LR 8

typedef __attribute__((ext_vector_type(8))) short bf16x8;
typedef __attribute__((ext_vector_type(4))) float f32x4;
typedef __attribute__((ext_vector_type(16))) float f32x16;

typedef __attribute__((address_space(3))) void lds_void;
typedef const __attribute__((address_space(1))) void glb_void;

static __device__ __forceinline__ float bf2f(__hip_bfloat16 v) { return __bfloat162float(v); }
static __device__ __forceinline__ __hip_bfloat16 f2bf(float v) { return __float2bfloat16(v); }

static __device__ __forceinline__ unsigned pkbf(float lo, float hi2) {
  __hip_bfloat16 l = __float2bfloat16(lo), h2 = __float2bfloat16(hi2);
  unsigned short ul = *reinterpret_cast<unsigned short*>(&l);
  unsigned short uh = *reinterpret_cast<unsigned short*>(&h2);
  return ((unsigned)uh << 16) | ul;
}

static __device__ __forceinline__ float bfbits2f(short s) {
  union { unsigned u; float f; } c;
  c.u = ((unsigned)(unsigned short)s) << 16;
  return c.f;
}

// ---------------------------------------------------------------- fp32 -> bf16 (Wo)
__global__ __launch_bounds__(256) void conv_f32_bf16(const float* __restrict__ src,
                                                     __hip_bfloat16* __restrict__ dst,
                                                     int n4) {
  const int i = blockIdx.x * 256 + threadIdx.x;
  if (i >= n4) return;
  const float4 v = reinterpret_cast<const float4*>(src)[i];
  union { __hip_bfloat16 h[4]; ushort4 u; } pk;
  pk.h[0] = f2bf(v.x); pk.h[1] = f2bf(v.y); pk.h[2] = f2bf(v.z); pk.h[3] = f2bf(v.w);
  reinterpret_cast<ushort4*>(dst)[i] = pk.u;
}

// ---------------------------------------------------------------- fp32 -> bf16, 3 weights, one dispatch
__global__ __launch_bounds__(256) void conv_w3(const float* __restrict__ w0,
                                               const float* __restrict__ w1,
                                               const float* __restrict__ w2,
                                               __hip_bfloat16* __restrict__ dst) {
  const int z = blockIdx.z;
  const float* src = (z == 0) ? w0 : (z == 1) ? w1 : w2;
  __hip_bfloat16* d = dst + (size_t)z * HID * HID;
  const int i = blockIdx.x * 256 + threadIdx.x;  // over HID*HID/4
  const float4 v = reinterpret_cast<const float4*>(src)[i];
  union { __hip_bfloat16 h[4]; ushort4 u; } pk;
  pk.h[0] = f2bf(v.x); pk.h[1] = f2bf(v.y); pk.h[2] = f2bf(v.z); pk.h[3] = f2bf(v.w);
  reinterpret_cast<ushort4*>(d)[i] = pk.u;
}

// ---------------------------------------------------------------- t = x @ A^T (fp32, rank 8) + x->bf16
// (R18 form: 3 wave-groups, one per {Aq,Ak,Av}; which==0 also emits xb. TLP-rich.)
__global__ __launch_bounds__(256) void lora_t(const float* __restrict__ x,
                                              const float* __restrict__ Aq,
                                              const float* __restrict__ Ak,
                                              const float* __restrict__ Av,
                                              float* __restrict__ tq,
                                              float* __restrict__ tk,
                                              float* __restrict__ tv,
                                              __hip_bfloat16* __restrict__ xb) {
  const int gw = blockIdx.x * 4 + (threadIdx.x >> 6);
  const int lane = threadIdx.x & 63;
  const int which = gw / SEQ;
  const int s = gw - which * SEQ;
  const float* A = (which == 0) ? Aq : (which == 1) ? Ak : Av;
  float* t = (which == 0) ? tq : (which == 1) ? tk : tv;
  float acc[LR];
#pragma unroll
  for (int r = 0; r < LR; ++r) acc[r] = 0.0f;
  const float4* xr = reinterpret_cast<const float4*>(x + (size_t)s * HID);
  for (int c = lane; c < HID / 4; c += 64) {
    const float4 xv = xr[c];
    if (which == 0) {
      union { __hip_bfloat16 h[4]; ushort4 u; } pk;
      pk.h[0] = f2bf(xv.x); pk.h[1] = f2bf(xv.y); pk.h[2] = f2bf(xv.z); pk.h[3] = f2bf(xv.w);
      reinterpret_cast<ushort4*>(xb + (size_t)s * HID)[c] = pk.u;
    }
#pragma unroll
    for (int r = 0; r < LR; ++r) {
      const float4 av = reinterpret_cast<const float4*>(A + r * HID)[c];
      acc[r] += xv.x * av.x + xv.y * av.y + xv.z * av.z + xv.w * av.w;
    }
  }
#pragma unroll
  for (int r = 0; r < LR; ++r) {
    float vv = acc[r];
#pragma unroll
    for (int off = 32; off > 0; off >>= 1) vv += __shfl_down(vv, off);
    if (lane == 0) t[s * LR + r] = vv;
  }
}

// ---------------------------------------------------------------- RoPE cos/sin tables [S][64]
__global__ __launch_bounds__(256) void rope_tables(float* __restrict__ cosb,
                                                   float* __restrict__ sinb) {
  const int i = blockIdx.x * 256 + threadIdx.x;
  const int s = i >> 6, d = i & 63;
  const float invf = powf(10000.0f, -(float)d * (1.0f / 64.0f));
  const float ang = (float)s * invf;
  cosb[i] = cosf(ang);
  sinb[i] = sinf(ang);
}

// ---------------------------------------------------------------- counted-vmcnt GEMM (R7 core)
// BM=128 BN=256 BK=64, 8 waves; vmcnt(3) counted waits; T2 both-sides swizzle;
// XCD col-panel L2 map. z==2 (V): epilogue writes transpose directly.
// z==1 (K): epilogue applies RoPE via LDS pair-exchange.
template <bool LORA>
__global__ __launch_bounds__(512, 2) void gemm2(const __hip_bfloat16* __restrict__ X,
                                                const __hip_bfloat16* __restrict__ wqkv,
                                                const float* __restrict__ tq,
                                                const float* __restrict__ tk,
                                                const float* __restrict__ tv,
                                                const float* __restrict__ Bq,
                                                const float* __restrict__ Bk,
                                                const float* __restrict__ Bv,
                                                const float* __restrict__ cosb,
                                                const float* __restrict__ sinb,
                                                __hip_bfloat16* __restrict__ qb,
                                                __hip_bfloat16* __restrict__ kb,
                                                __hip_bfloat16* __restrict__ vtb,
                                                float* __restrict__ outf) {
  __shared__ __hip_bfloat16 Al[2][2][128][32];
  __shared__ __hip_bfloat16 Bl[2][2][256][32];
  const int z = blockIdx.z;
  const __hip_bfloat16* W = wqkv + (size_t)z * HID * HID;
  const float* T = (z == 0) ? tq : (z == 1) ? tk : tv;
  const float* BL = (z == 0) ? Bq : (z == 1) ? Bk : Bv;

  const int tid = threadIdx.x;
  const int lane = tid & 63;
  const int w = tid >> 6;
  const int wm = w >> 2;
  const int wn = w & 3;
  const int g = lane >> 4, lr = lane & 15;

  const int fid = blockIdx.x + (blockIdx.y << 4);
  const int xcd = fid & 7;
  const int j8 = fid >> 3;
  const int rowBase = (j8 >> 1) * 128;
  const int colBase = (xcd * 2 + (j8 & 1)) * 256;

  const int sA = w * 64 + lane;
  const int rA = sA >> 2, cA = sA & 3;
  const __hip_bfloat16* Ag = X + (size_t)(rowBase + rA) * HID + ((cA ^ ((rA >> 1) & 3)) * 8);
  const int sB0 = (w * 2) * 64 + lane;
  const int sB1 = (w * 2 + 1) * 64 + lane;
  const int rB0 = sB0 >> 2, cB0 = sB0 & 3;
  const int rB1 = sB1 >> 2, cB1 = sB1 & 3;
  const __hip_bfloat16* Bg0 = W + (size_t)(colBase + rB0) * HID + ((cB0 ^ ((rB0 >> 1) & 3)) * 8);
  const __hip_bfloat16* Bg1 = W + (size_t)(colBase + rB1) * HID + ((cB1 ^ ((rB1 >> 1) & 3)) * 8);

#define STG2(buf_, kh_, kk_)                                                        \
  do {                                                                              \
    __builtin_amdgcn_global_load_lds((glb_void*)(Ag + (kk_) + (kh_) * 32),          \
        (lds_void*)(&Al[buf_][kh_][0][0] + w * 512), 16, 0, 0);                     \
    __builtin_amdgcn_global_load_lds((glb_void*)(Bg0 + (kk_) + (kh_) * 32),         \
        (lds_void*)(&Bl[buf_][kh_][0][0] + (w * 2) * 512), 16, 0, 0);               \
    __builtin_amdgcn_global_load_lds((glb_void*)(Bg1 + (kk_) + (kh_) * 32),         \
        (lds_void*)(&Bl[buf_][kh_][0][0] + (w * 2 + 1) * 512), 16, 0, 0);           \
  } while (0)

  f32x4 acc[4][4];
#pragma unroll
  for (int m = 0; m < 4; ++m)
#pragma unroll
    for (int n = 0; n < 4; ++n)
#pragma unroll
      for (int e = 0; e < 4; ++e) acc[m][n][e] = 0.0f;

  const int ch = (g ^ ((lr >> 1) & 3)) * 8;

  STG2(0, 0, 0);
  __builtin_amdgcn_sched_barrier(0);
  STG2(0, 1, 0);

  for (int j = 0; j < 64; ++j) {
    const int cur = j & 1, nxt = cur ^ 1;
    const int kn = (j < 63 ? j + 1 : 63) * 64;  // j==63: redundant re-stage keeps FIFO
#pragma unroll
    for (int kh = 0; kh < 2; ++kh) {
      asm volatile("s_waitcnt vmcnt(3) lgkmcnt(0)" ::: "memory");
      __builtin_amdgcn_s_barrier();
      __builtin_amdgcn_sched_barrier(0);
      bf16x8 af[4], bfr[4];
#pragma unroll
      for (int m = 0; m < 4; ++m)
        af[m] = *reinterpret_cast<const bf16x8*>(&Al[cur][kh][wm * 64 + m * 16 + lr][ch]);
#pragma unroll
      for (int n = 0; n < 4; ++n)
        bfr[n] = *reinterpret_cast<const bf16x8*>(&Bl[cur][kh][wn * 64 + n * 16 + lr][ch]);
      if (kh == 0) STG2(nxt, 0, kn); else STG2(nxt, 1, kn);
      __builtin_amdgcn_sched_barrier(0);
      __builtin_amdgcn_s_setprio(1);
#pragma unroll
      for (int m = 0; m < 4; ++m)
#pragma unroll
        for (int n = 0; n < 4; ++n)
          acc[m][n] = __builtin_amdgcn_mfma_f32_16x16x32_bf16(af[m], bfr[n], acc[m][n], 0, 0, 0);
      __builtin_amdgcn_s_setprio(0);
    }
  }
#undef STG2

  const int orow0 = rowBase + wm * 64 + g * 4;
  const int ocol0 = colBase + wn * 64 + lr;
  if constexpr (LORA) {
    float bl[4][8];
#pragma unroll
    for (int n = 0; n < 4; ++n) {
      const int cc = ocol0 + n * 16;
      const int fc = (cc < HID / 2) ? (2 * cc) : (2 * (cc - HID / 2) + 1);
#pragma unroll
      for (int e = 0; e < 8; ++e) bl[n][e] = BL[fc * LR + e];
    }
    __hip_bfloat16 vv[4][4][4];
#pragma unroll
    for (int m = 0; m < 4; ++m) {
      float tr[4][8];
#pragma unroll
      for (int r2 = 0; r2 < 4; ++r2)
#pragma unroll
        for (int e = 0; e < 8; ++e) tr[r2][e] = T[(size_t)(orow0 + m * 16 + r2) * LR + e];
#pragma unroll
      for (int n = 0; n < 4; ++n)
#pragma unroll
        for (int r2 = 0; r2 < 4; ++r2) {
          float dot = 0.0f;
#pragma unroll
          for (int e = 0; e < 8; ++e) dot += tr[r2][e] * bl[n][e];
          vv[m][n][r2] = f2bf(acc[m][n][r2] + 2.0f * dot);
        }
    }
    if (z == 0) {
#pragma unroll
      for (int m = 0; m < 4; ++m)
#pragma unroll
        for (int n = 0; n < 4; ++n)
#pragma unroll
          for (int r2 = 0; r2 < 4; ++r2)
            qb[(size_t)(orow0 + m * 16 + r2) * HID + ocol0 + n * 16] = vv[m][n][r2];
    } else if (z == 2) {
#pragma unroll
      for (int m = 0; m < 4; ++m)
#pragma unroll
        for (int n = 0; n < 4; ++n) {
          const int cc = ocol0 + n * 16;
          union { __hip_bfloat16 h[4]; ushort4 u; } pk;
#pragma unroll
          for (int r2 = 0; r2 < 4; ++r2) pk.h[r2] = vv[m][n][r2];
          *reinterpret_cast<ushort4*>(vtb + (size_t)cc * SEQ + orow0 + m * 16) = pk.u;
        }
    } else {
      // K: RoPE via LDS pair-exchange; drain pending gload_lds into buffer 0 first
      asm volatile("s_waitcnt vmcnt(0)" ::: "memory");
      __syncthreads();
      __hip_bfloat16* ex = &Bl[0][0][0][0];  // 64 KB = [128][256]
#pragma unroll
      for (int m = 0; m < 4; ++m)
#pragma unroll
        for (int n = 0; n < 4; ++n) {
          const int rl = wm * 64 + m * 16 + g * 4;
          const int ccl = wn * 64 + n * 16 + lr;
#pragma unroll
          for (int r2 = 0; r2 < 4; ++r2) ex[(rl + r2) * 256 + ccl] = vv[m][n][r2];
        }
      __syncthreads();
#pragma unroll
      for (int m = 0; m < 4; ++m)
#pragma unroll
        for (int n = 0; n < 4; ++n) {
          const int rl = wm * 64 + m * 16 + g * 4;
          const int ccl = wn * 64 + n * 16 + lr;
          const int d = ccl & 127;
          const int dd = d & 63;
#pragma unroll
          for (int r2 = 0; r2 < 4; ++r2) {
            const int rowg = rowBase + rl + r2;
            const float c = cosb[(size_t)rowg * 64 + dd];
            const float s = sinb[(size_t)rowg * 64 + dd];
            const float v0 = bf2f(vv[m][n][r2]);
            const float pv = bf2f(ex[(rl + r2) * 256 + (ccl ^ 64)]);
            const float outv = (d < 64) ? (v0 * c - pv * s) : (pv * s + v0 * c);
            kb[(size_t)rowg * HID + colBase + ccl] = f2bf(outv);
          }
        }
    }
  } else {
#pragma unroll
    for (int m = 0; m < 4; ++m)
#pragma unroll
      for (int n = 0; n < 4; ++n)
#pragma unroll
        for (int r2 = 0; r2 < 4; ++r2)
          outf[(size_t)(orow0 + m * 16 + r2) * HID + ocol0 + n * 16] = acc[m][n][r2];
  }
}

// ---------------------------------------------------------------- causal flash attention v4 + q-RoPE
#define STAGE(buf_, kvb_)                                                                   \
  do {                                                                                      \
    _Pragma("unroll") for (int i_ = 0; i_ < 4; ++i_) {                                      \
      const int sb_ = (w * 4 + i_) * 64;                                                    \
      {                                                                                     \
        const int slot_ = sb_ + lane;                                                       \
        const int rr_ = slot_ >> 4, cc_ = slot_ & 15;                                       \
        __builtin_amdgcn_global_load_lds(                                                   \
            (glb_void*)(kg + (size_t)((kvb_) + rr_) * HID + h * HDIM +                      \
                        ((cc_ ^ (rr_ & 15)) << 3)),                                         \
            (lds_void*)(&Ks[buf_][sb_ * 8]), 16, 0, 0);                                     \
      }                                                                                     \
      {                                                                                     \
        const int slot_ = sb_ + lane;                                                       \
        const int rr_ = slot_ >> 3, cc_ = slot_ & 7;                                        \
        __builtin_amdgcn_global_load_lds(                                                   \
            (glb_void*)(vt + ((size_t)h * HDIM + rr_) * SEQ + (kvb_) +                      \
                        ((cc_ ^ (rr_ & 7)) << 3)),                                          \
            (lds_void*)(&Vs[buf_][sb_ * 8]), 16, 0, 0);                                     \
      }                                                                                     \
    }                                                                                       \
  } while (0)

__global__ __launch_bounds__(256, 2) void flash_attn4(const __hip_bfloat16* __restrict__ qg,
                                                      const __hip_bfloat16* __restrict__ kg,
                                                      const __hip_bfloat16* __restrict__ vt,
                                                      const float* __restrict__ cosb,
                                                      const float* __restrict__ sinb,
                                                      __hip_bfloat16* __restrict__ o) {
  __shared__ __hip_bfloat16 Ks[2][64 * 128];
  __shared__ __hip_bfloat16 Vs[2][128 * 64];
  const int tid = threadIdx.x;
  const int lane = tid & 63;
  const int w = tid >> 6;
  const int ql = lane & 31;
  const int hi = lane >> 5;
  const int bx = blockIdx.x;
  const int h = bx & 31;
  const int strip = (bx < 256) ? (bx >> 5) : (15 - ((bx - 256) >> 5));
  const float scale = 0.088388347648318447f;

  const int q0 = strip * 128 + w * 32;
  const int nt = 2 * strip + 2;
  const int qgl = q0 + ql;

  bf16x8 bq[8];
#pragma unroll
  for (int sl = 0; sl < 8; ++sl)
    bq[sl] = *reinterpret_cast<const bf16x8*>(qg + (size_t)qgl * HID + h * HDIM + sl * 16 + hi * 8);

  // ---- q-RoPE in registers: pair (bq[sl], bq[sl+4]); cos/sin at d = sl*16+hi*8+e
  {
    const float* cb = cosb + (size_t)qgl * 64;
    const float* sbl = sinb + (size_t)qgl * 64;
#pragma unroll
    for (int sl = 0; sl < 4; ++sl) {
      const int d0 = sl * 16 + hi * 8;
      const float4 c0 = *reinterpret_cast<const float4*>(cb + d0);
      const float4 c1 = *reinterpret_cast<const float4*>(cb + d0 + 4);
      const float4 s0 = *reinterpret_cast<const float4*>(sbl + d0);
      const float4 s1 = *reinterpret_cast<const float4*>(sbl + d0 + 4);
      const float cc[8] = {c0.x, c0.y, c0.z, c0.w, c1.x, c1.y, c1.z, c1.w};
      const float ss[8] = {s0.x, s0.y, s0.z, s0.w, s1.x, s1.y, s1.z, s1.w};
      float y1[8], y2[8];
#pragma unroll
      for (int e = 0; e < 8; ++e) {
        const float x1 = bfbits2f(bq[sl][e]);
        const float x2 = bfbits2f(bq[sl + 4][e]);
        y1[e] = x1 * cc[e] - x2 * ss[e];
        y2[e] = x1 * ss[e] + x2 * cc[e];
      }
      union { unsigned u[4]; bf16x8 v; } p1, p2;
#pragma unroll
      for (int e2 = 0; e2 < 4; ++e2) {
        p1.u[e2] = pkbf(y1[2 * e2], y1[2 * e2 + 1]);
        p2.u[e2] = pkbf(y2[2 * e2], y2[2 * e2 + 1]);
      }
      bq[sl] = p1.v;
      bq[sl + 4] = p2.v;
    }
  }

  f32x16 accO[4];
#pragma unroll
  for (int db = 0; db < 4; ++db)
#pragma unroll
    for (int e = 0; e < 16; ++e) accO[db][e] = 0.0f;
  float m_run = -1e30f, lsum = 0.0f;

  int cur = 0;
  STAGE(0, 0);
  asm volatile("s_waitcnt vmcnt(0)");
  __syncthreads();

  for (int t = 0; t < nt; ++t) {
    const int kvb = t * 64;
    if (t + 1 < nt) STAGE(cur ^ 1, (t + 1) * 64);
    if (kvb <= q0 + 31) {
      f32x16 sc[2];
#pragma unroll
      for (int sub = 0; sub < 2; ++sub) {
#pragma unroll
        for (int e = 0; e < 16; ++e) sc[sub][e] = 0.0f;
        const int krow = sub * 32 + ql;
#pragma unroll
        for (int sl = 0; sl < 8; ++sl) {
          const int chh = (sl * 2 + hi) ^ (ql & 15);
          bf16x8 ak = *reinterpret_cast<const bf16x8*>(&Ks[cur][krow * 128 + chh * 8]);
          sc[sub] = __builtin_amdgcn_mfma_f32_32x32x16_bf16(ak, bq[sl], sc[sub], 0, 0, 0);
        }
      }
      float smax = -3.0e38f;
      if (kvb + 63 > q0) {
#pragma unroll
        for (int sub = 0; sub < 2; ++sub)
#pragma unroll
          for (int r = 0; r < 16; ++r) {
            const int kvg = kvb + sub * 32 + (r & 3) + 8 * (r >> 2) + 4 * hi;
            float v2 = sc[sub][r] * scale;
            v2 = (kvg > qgl) ? -3.0e38f : v2;
            sc[sub][r] = v2;
            smax = fmaxf(smax, v2);
          }
      } else {
#pragma unroll
        for (int sub = 0; sub < 2; ++sub)
#pragma unroll
          for (int r = 0; r < 16; ++r) {
            const float v2 = sc[sub][r] * scale;
            sc[sub][r] = v2;
            smax = fmaxf(smax, v2);
          }
      }
      smax = fmaxf(smax, __shfl_xor(smax, 32));
      if (__any(smax > m_run + 8.0f)) {
        const float mnew = fmaxf(m_run, smax);
        const float sca = __expf(m_run - mnew);
        m_run = mnew;
        lsum *= sca;
#pragma unroll
        for (int r = 0; r < 16; ++r) {
          const float sr = __shfl(sca, (r & 3) + 8 * (r >> 2) + 4 * hi);
#pragma unroll
          for (int db = 0; db < 4; ++db) accO[db][r] *= sr;
        }
      }
      float psum = 0.0f;
#pragma unroll
      for (int sub = 0; sub < 2; ++sub)
#pragma unroll
        for (int r = 0; r < 16; ++r) {
          const float p = __expf(sc[sub][r] - m_run);
          sc[sub][r] = p;
          psum += p;
        }
      psum += __shfl_xor(psum, 32);
      lsum += psum;
      bf16x8 pa[4];
#pragma unroll
      for (int sub = 0; sub < 2; ++sub) {
        const unsigned A0 = pkbf(sc[sub][0], sc[sub][1]);
        const unsigned C0 = pkbf(sc[sub][2], sc[sub][3]);
        const unsigned B0 = pkbf(sc[sub][4], sc[sub][5]);
        const unsigned D0 = pkbf(sc[sub][6], sc[sub][7]);
        const unsigned A1 = pkbf(sc[sub][8], sc[sub][9]);
        const unsigned C1 = pkbf(sc[sub][10], sc[sub][11]);
        const unsigned B1 = pkbf(sc[sub][12], sc[sub][13]);
        const unsigned D1 = pkbf(sc[sub][14], sc[sub][15]);
        const unsigned sA0 = (unsigned)__shfl_xor((int)A0, 32);
        const unsigned sB0 = (unsigned)__shfl_xor((int)B0, 32);
        const unsigned sC0 = (unsigned)__shfl_xor((int)C0, 32);
        const unsigned sD0 = (unsigned)__shfl_xor((int)D0, 32);
        const unsigned sA1 = (unsigned)__shfl_xor((int)A1, 32);
        const unsigned sB1 = (unsigned)__shfl_xor((int)B1, 32);
        const unsigned sC1 = (unsigned)__shfl_xor((int)C1, 32);
        const unsigned sD1 = (unsigned)__shfl_xor((int)D1, 32);
        union { unsigned u[4]; bf16x8 v; } f0, f1;
        f0.u[0] = hi ? sB0 : A0;
        f0.u[1] = hi ? sD0 : C0;
        f0.u[2] = hi ? B0 : sA0;
        f0.u[3] = hi ? D0 : sC0;
        f1.u[0] = hi ? sB1 : A1;
        f1.u[1] = hi ? sD1 : C1;
        f1.u[2] = hi ? B1 : sA1;
        f1.u[3] = hi ? D1 : sC1;
        pa[sub * 2 + 0] = f0.v;
        pa[sub * 2 + 1] = f1.v;
      }
#pragma unroll
      for (int db = 0; db < 4; ++db) {
        const int vrow = db * 32 + ql;
#pragma unroll
        for (int ks = 0; ks < 4; ++ks) {
          const int chh = (ks * 2 + hi) ^ (ql & 7);
          bf16x8 bv = *reinterpret_cast<const bf16x8*>(&Vs[cur][vrow * 64 + chh * 8]);
          accO[db] = __builtin_amdgcn_mfma_f32_32x32x16_bf16(pa[ks], bv, accO[db], 0, 0, 0);
        }
      }
    }
    asm volatile("s_waitcnt vmcnt(0)");
    __syncthreads();
    cur ^= 1;
  }
  const float il = 1.0f / lsum;
#pragma unroll
  for (int r = 0; r < 16; ++r) {
    const int rb = (r & 3) + 8 * (r >> 2);
    const float ir = __shfl(il, rb + 4 * hi);
    const int qrow = q0 + rb + 4 * hi;
#pragma unroll
    for (int db = 0; db < 4; ++db)
      o[(size_t)qrow * HID + h * HDIM + db * 32 + ql] = f2bf(accO[db][r] * ir);
  }
}

// ----------------------------------------------------------------
extern "C" void kernel_launch(void* const* d_in, const int* in_sizes, int n_in,
                              void* d_out, int out_size, void* d_ws, size_t ws_size,
                              hipStream_t stream) {
  (void)in_sizes; (void)n_in; (void)out_size; (void)ws_size;
  const float* x  = (const float*)d_in[0];
  const float* Wq = (const float*)d_in[1];
  const float* Wk = (const float*)d_in[2];
  const float* Wv = (const float*)d_in[3];
  const float* Wo = (const float*)d_in[4];
  const float* Aq = (const float*)d_in[5];
  const float* Bq = (const float*)d_in[6];
  const float* Ak = (const float*)d_in[7];
  const float* Bk = (const float*)d_in[8];
  const float* Av = (const float*)d_in[9];
  const float* Bv = (const float*)d_in[10];
  float* out = (float*)d_out;

  char* p = (char*)d_ws;
  __hip_bfloat16* xb   = (__hip_bfloat16*)p; p += (size_t)SEQ * HID * 2;       // reused as ab
  __hip_bfloat16* wqkv = (__hip_bfloat16*)p; p += (size_t)3 * HID * HID * 2;   // [0:32M] reused for Wo
  __hip_bfloat16* qb   = (__hip_bfloat16*)p; p += (size_t)SEQ * HID * 2;
  __hip_bfloat16* kb   = (__hip_bfloat16*)p; p += (size_t)SEQ * HID * 2;
  __hip_bfloat16* vtb  = (__hip_bfloat16*)p; p += (size_t)SEQ * HID * 2;       // V^T, written by gemm z==2
  float* tq   = (float*)p; p += SEQ * LR * 4;
  float* tk   = (float*)p; p += SEQ * LR * 4;
  float* tv   = (float*)p; p += SEQ * LR * 4;
  float* cosb = (float*)p; p += SEQ * 64 * 4;
  float* sinb = (float*)p; p += SEQ * 64 * 4;
  __hip_bfloat16* ab = xb;  // x no longer needed after QKV GEMMs

  lora_t<<<SEQ * 3 / 4, 256, 0, stream>>>(x, Aq, Ak, Av, tq, tk, tv, xb);
  rope_tables<<<SEQ * 64 / 256, 256, 0, stream>>>(cosb, sinb);
  conv_w3<<<dim3(HID * HID / 1024, 1, 3), 256, 0, stream>>>(Wq, Wk, Wv, wqkv);

  gemm2<true><<<dim3(16, 16, 3), 512, 0, stream>>>(xb, wqkv, tq, tk, tv, Bq, Bk, Bv,
                                                   cosb, sinb, qb, kb, vtb, nullptr);

  flash_attn4<<<512, 256, 0, stream>>>(qb, kb, vtb, cosb, sinb, ab);

  conv_f32_bf16<<<HID * HID / 1024, 256, 0, stream>>>(Wo, wqkv, HID * HID / 4);
  gemm2<false><<<dim3(16, 16, 1), 512, 0, stream>>>(ab, wqkv, nullptr, nullptr, nullptr,
                                                    nullptr, nullptr, nullptr,
                                                    cosb, sinb, nullptr, nullptr, nullptr, out);
}